// Round 1
// baseline (206.058 us; speedup 1.0000x reference)
//
#include <hip/hip_runtime.h>
#include <math.h>

#define EPSBN 1e-5f

constexpr int B   = 2;
constexpr int C1  = 60;          // x1 channels
constexpr int NV  = 64 * 64 * 64; // voxels per batch (D/2 * H/2 * W)
constexpr int NBLK = NV / 256;    // 1024 blocks per batch

// ---------------------------------------------------------------------------
// Kernel A: DWT + BN + ReLU + LL out + conv0 (1x1x1, 64->4) + channel partial sums
// dwt, s0 stored channel-last: [b][voxel][4] (float4)
// part stored [b][blk][64]
// ---------------------------------------------------------------------------
__global__ __launch_bounds__(256) void kA(
    const float* __restrict__ x1, const float* __restrict__ x2,
    const float* __restrict__ bn_g, const float* __restrict__ bn_b,
    const float* __restrict__ bn_m, const float* __restrict__ bn_v,
    const float* __restrict__ sg_w0, const float* __restrict__ sg_b0,
    const float* __restrict__ sg_g0, const float* __restrict__ sg_be0,
    const float* __restrict__ sg_m0, const float* __restrict__ sg_v0,
    float* __restrict__ dwt, float* __restrict__ s0,
    float* __restrict__ part, float* __restrict__ outLL)
{
    __shared__ float w0l[256];      // [r][c] = sg_w0[r*64+c]
    __shared__ float cA[4], cB[4];  // s0 = relu(acc*cA + cB)
    __shared__ float dsc[4], dsh[4];
    __shared__ float wsum[64][4];

    const int tid = threadIdx.x;
    w0l[tid] = sg_w0[tid];
    if (tid < 4) {
        float sc = sg_g0[tid] * rsqrtf(sg_v0[tid] + EPSBN);
        cA[tid] = sc;
        cB[tid] = (sg_b0[tid] - sg_m0[tid]) * sc + sg_be0[tid];
        float d = bn_g[tid] * rsqrtf(bn_v[tid] + EPSBN);
        dsc[tid] = d;
        dsh[tid] = bn_b[tid] - bn_m[tid] * d;
    }
    __syncthreads();

    const int b = blockIdx.y;
    const int s = blockIdx.x * 256 + tid;     // voxel index within batch
    const int x = s & 63, y = (s >> 6) & 63, z = s >> 12;
    const int lane = tid & 63, wv = tid >> 6;

    // Haar DWT2 over (D,H)
    const float* px2 = x2 + (size_t)b * (128 * 128 * 64);
    const size_t i00 = ((size_t)(2 * z) * 128 + 2 * y) * 64 + x;
    const float p00 = px2[i00], p01 = px2[i00 + 64];
    const float p10 = px2[i00 + 8192], p11 = px2[i00 + 8192 + 64];
    const float LL = 0.5f * (p00 + p01 + p10 + p11);
    const float LH = 0.5f * (p00 + p01 - p10 - p11);
    const float HL = 0.5f * (p00 - p01 + p10 - p11);
    const float HH = 0.5f * (p00 - p01 - p10 + p11);
    outLL[(size_t)b * NV + s] = LL;

    float dv[4] = { LL, LH, HL, HH };
    float acc[4] = { 0.f, 0.f, 0.f, 0.f };

    #pragma unroll
    for (int c = 0; c < 4; ++c) {
        float t = fmaxf(dv[c] * dsc[c] + dsh[c], 0.f);  // BN + ReLU
        dv[c] = t;
        #pragma unroll
        for (int r = 0; r < 4; ++r) acc[r] += w0l[r * 64 + c] * t;
        float rs = t;
        #pragma unroll
        for (int off = 32; off; off >>= 1) rs += __shfl_xor(rs, off);
        if (lane == 0) wsum[c][wv] = rs;
    }

    ((float4*)dwt)[(size_t)b * NV + s] = make_float4(dv[0], dv[1], dv[2], dv[3]);

    const float* px1 = x1 + (size_t)b * C1 * NV + s;
    for (int c = 0; c < C1; ++c) {
        float v = px1[(size_t)c * NV];
        #pragma unroll
        for (int r = 0; r < 4; ++r) acc[r] += w0l[r * 64 + 4 + c] * v;
        float rs = v;
        #pragma unroll
        for (int off = 32; off; off >>= 1) rs += __shfl_xor(rs, off);
        if (lane == 0) wsum[4 + c][wv] = rs;
    }

    float4 sq;
    sq.x = fmaxf(acc[0] * cA[0] + cB[0], 0.f);
    sq.y = fmaxf(acc[1] * cA[1] + cB[1], 0.f);
    sq.z = fmaxf(acc[2] * cA[2] + cB[2], 0.f);
    sq.w = fmaxf(acc[3] * cA[3] + cB[3], 0.f);
    ((float4*)s0)[(size_t)b * NV + s] = sq;

    __syncthreads();
    if (tid < 64) {
        float p = wsum[tid][0] + wsum[tid][1] + wsum[tid][2] + wsum[tid][3];
        part[((size_t)b * NBLK + blockIdx.x) * 64 + tid] = p;
    }
}

// ---------------------------------------------------------------------------
// Dilated 3x3x3 conv (dil=4, pad=4), 4->4 ch, + BN + ReLU.
// FUSE3: additionally apply the final 1x1x1 conv (4->1) -> att_s scalar out.
// ---------------------------------------------------------------------------
template <bool FUSE3>
__global__ __launch_bounds__(256) void kConv(
    const float* __restrict__ sin_,
    const float* __restrict__ w, const float* __restrict__ bias,
    const float* __restrict__ g, const float* __restrict__ be,
    const float* __restrict__ m, const float* __restrict__ vv,
    const float* __restrict__ w3, const float* __restrict__ b3,
    float* __restrict__ outp)
{
    __shared__ float wl[432];       // [r][q][t] = w[r*108 + q*27 + t]
    __shared__ float cA[4], cB[4], w3l[4];
    __shared__ float b3l;

    const int tid = threadIdx.x;
    for (int i = tid; i < 432; i += 256) wl[i] = w[i];
    if (tid < 4) {
        float sc = g[tid] * rsqrtf(vv[tid] + EPSBN);
        cA[tid] = sc;
        cB[tid] = (bias[tid] - m[tid]) * sc + be[tid];
        if (FUSE3) w3l[tid] = w3[tid];
    }
    if (FUSE3 && tid == 0) b3l = b3[0];
    __syncthreads();

    const int b = blockIdx.y;
    const int s = blockIdx.x * 256 + tid;
    const int x = s & 63, y = (s >> 6) & 63, z = s >> 12;
    const float4* pin = (const float4*)sin_ + (size_t)b * NV;

    float a0 = 0.f, a1 = 0.f, a2 = 0.f, a3 = 0.f;
    #pragma unroll
    for (int kz = -1; kz <= 1; ++kz) {
        int zz = z + 4 * kz;
        if ((unsigned)zz >= 64u) continue;
        #pragma unroll
        for (int ky = -1; ky <= 1; ++ky) {
            int yy = y + 4 * ky;
            if ((unsigned)yy >= 64u) continue;
            #pragma unroll
            for (int kx = -1; kx <= 1; ++kx) {
                int xx = x + 4 * kx;
                if ((unsigned)xx >= 64u) continue;
                float4 v = pin[zz * 4096 + yy * 64 + xx];
                int t = (kz + 1) * 9 + (ky + 1) * 3 + (kx + 1);
                a0 += wl[      t] * v.x + wl[ 27 + t] * v.y + wl[ 54 + t] * v.z + wl[ 81 + t] * v.w;
                a1 += wl[108 + t] * v.x + wl[135 + t] * v.y + wl[162 + t] * v.z + wl[189 + t] * v.w;
                a2 += wl[216 + t] * v.x + wl[243 + t] * v.y + wl[270 + t] * v.z + wl[297 + t] * v.w;
                a3 += wl[324 + t] * v.x + wl[351 + t] * v.y + wl[378 + t] * v.z + wl[405 + t] * v.w;
            }
        }
    }

    float r0 = fmaxf(a0 * cA[0] + cB[0], 0.f);
    float r1 = fmaxf(a1 * cA[1] + cB[1], 0.f);
    float r2 = fmaxf(a2 * cA[2] + cB[2], 0.f);
    float r3 = fmaxf(a3 * cA[3] + cB[3], 0.f);

    if (FUSE3) {
        outp[(size_t)b * NV + s] = b3l + w3l[0] * r0 + w3l[1] * r1 + w3l[2] * r2 + w3l[3] * r3;
    } else {
        ((float4*)outp)[(size_t)b * NV + s] = make_float4(r0, r1, r2, r3);
    }
}

// ---------------------------------------------------------------------------
// Pooled-mean reduction + channel-gate MLP -> att_c [B][64]
// ---------------------------------------------------------------------------
__global__ __launch_bounds__(256) void kMLP(
    const float* __restrict__ part,
    const float* __restrict__ cg_w1, const float* __restrict__ cg_b1,
    const float* __restrict__ cg_bng, const float* __restrict__ cg_bnb,
    const float* __restrict__ cg_bnm, const float* __restrict__ cg_bnv,
    const float* __restrict__ cg_w2, const float* __restrict__ cg_b2,
    float* __restrict__ att_c)
{
    const int b = blockIdx.x;
    const int tid = threadIdx.x;
    __shared__ float ps[4][64];
    __shared__ float pooled[64];
    __shared__ float h[4];

    const int c = tid & 63, k = tid >> 6;
    const float* pp = part + (size_t)b * NBLK * 64;
    float sm = 0.f;
    for (int i = k; i < NBLK; i += 4) sm += pp[(size_t)i * 64 + c];
    ps[k][c] = sm;
    __syncthreads();
    if (tid < 64) pooled[tid] = (ps[0][tid] + ps[1][tid] + ps[2][tid] + ps[3][tid]) * (1.0f / NV);
    __syncthreads();
    if (tid < 4) {
        float a = cg_b1[tid];
        for (int cc = 0; cc < 64; ++cc) a += pooled[cc] * cg_w1[tid * 64 + cc];
        float sc = cg_bng[tid] * rsqrtf(cg_bnv[tid] + EPSBN);
        h[tid] = fmaxf((a - cg_bnm[tid]) * sc + cg_bnb[tid], 0.f);
    }
    __syncthreads();
    if (tid < 64) {
        float a = cg_b2[tid];
        #pragma unroll
        for (int r = 0; r < 4; ++r) a += h[r] * cg_w2[tid * 4 + r];
        att_c[b * 64 + tid] = a;
    }
}

// ---------------------------------------------------------------------------
// Final: out[b][c][v] = feat * (1 + sigmoid(att_c[c] + att_s[v]))
// sigmoid(a+b) = 1 / (1 + e^{-a} e^{-b})
// ---------------------------------------------------------------------------
__global__ __launch_bounds__(256) void kFinal(
    const float* __restrict__ x1,
    const float* __restrict__ dwt,
    const float* __restrict__ att_s,
    const float* __restrict__ att_c,
    float* __restrict__ out0)
{
    __shared__ float ec[64];
    const int tid = threadIdx.x;
    const int b = blockIdx.y;
    if (tid < 64) ec[tid] = __expf(-att_c[b * 64 + tid]);
    __syncthreads();

    const size_t s = (size_t)blockIdx.x * 256 + tid;
    const float eas = __expf(-att_s[(size_t)b * NV + s]);
    const float4 dq = ((const float4*)dwt)[(size_t)b * NV + s];
    float* po = out0 + (size_t)b * 64 * NV + s;
    const float dv[4] = { dq.x, dq.y, dq.z, dq.w };
    #pragma unroll
    for (int c = 0; c < 4; ++c) {
        float sc = 1.f + 1.f / (1.f + ec[c] * eas);
        po[(size_t)c * NV] = dv[c] * sc;
    }
    const float* px1 = x1 + (size_t)b * C1 * NV + s;
    for (int c = 0; c < C1; ++c) {
        float sc = 1.f + 1.f / (1.f + ec[4 + c] * eas);
        po[(size_t)(4 + c) * NV] = px1[(size_t)c * NV] * sc;
    }
}

// ---------------------------------------------------------------------------
extern "C" void kernel_launch(void* const* d_in, const int* in_sizes, int n_in,
                              void* d_out, int out_size, void* d_ws, size_t ws_size,
                              hipStream_t stream)
{
    const float* x1 = (const float*)d_in[0];
    const float* x2 = (const float*)d_in[1];
    const float* bn_g = (const float*)d_in[2];
    const float* bn_b = (const float*)d_in[3];
    const float* bn_m = (const float*)d_in[4];
    const float* bn_v = (const float*)d_in[5];
    const float* cg_w1 = (const float*)d_in[6];
    const float* cg_b1 = (const float*)d_in[7];
    const float* cg_bng = (const float*)d_in[8];
    const float* cg_bnb = (const float*)d_in[9];
    const float* cg_bnm = (const float*)d_in[10];
    const float* cg_bnv = (const float*)d_in[11];
    const float* cg_w2 = (const float*)d_in[12];
    const float* cg_b2 = (const float*)d_in[13];
    const float* sg_w0 = (const float*)d_in[14];
    const float* sg_b0 = (const float*)d_in[15];
    const float* sg_g0 = (const float*)d_in[16];
    const float* sg_be0 = (const float*)d_in[17];
    const float* sg_m0 = (const float*)d_in[18];
    const float* sg_v0 = (const float*)d_in[19];
    const float* sg_w1 = (const float*)d_in[20];
    const float* sg_b1 = (const float*)d_in[21];
    const float* sg_g1 = (const float*)d_in[22];
    const float* sg_be1 = (const float*)d_in[23];
    const float* sg_m1 = (const float*)d_in[24];
    const float* sg_v1 = (const float*)d_in[25];
    const float* sg_w2 = (const float*)d_in[26];
    const float* sg_b2 = (const float*)d_in[27];
    const float* sg_g2 = (const float*)d_in[28];
    const float* sg_be2 = (const float*)d_in[29];
    const float* sg_m2 = (const float*)d_in[30];
    const float* sg_v2 = (const float*)d_in[31];
    const float* sg_w3 = (const float*)d_in[32];
    const float* sg_b3 = (const float*)d_in[33];

    float* ws = (float*)d_ws;
    float* dwt   = ws;                 // B*NV*4 = 2,097,152
    float* s0    = ws + 2097152;       // 2,097,152
    float* s1    = ws + 4194304;       // 2,097,152
    float* atts  = ws + 6291456;       // B*NV    =   524,288
    float* part  = ws + 6815744;       // B*NBLK*64 = 131,072
    float* attc  = ws + 6946816;       // 128

    float* out0  = (float*)d_out;
    float* outLL = out0 + (size_t)B * 64 * NV;   // 33,554,432

    dim3 grid(NBLK, B), blk(256);
    kA<<<grid, blk, 0, stream>>>(x1, x2, bn_g, bn_b, bn_m, bn_v,
                                 sg_w0, sg_b0, sg_g0, sg_be0, sg_m0, sg_v0,
                                 dwt, s0, part, outLL);
    kConv<false><<<grid, blk, 0, stream>>>(s0, sg_w1, sg_b1, sg_g1, sg_be1, sg_m1, sg_v1,
                                           nullptr, nullptr, s1);
    kConv<true><<<grid, blk, 0, stream>>>(s1, sg_w2, sg_b2, sg_g2, sg_be2, sg_m2, sg_v2,
                                          sg_w3, sg_b3, atts);
    kMLP<<<dim3(B), blk, 0, stream>>>(part, cg_w1, cg_b1, cg_bng, cg_bnb, cg_bnm, cg_bnv,
                                      cg_w2, cg_b2, attc);
    kFinal<<<grid, blk, 0, stream>>>(x1, dwt, atts, attc, out0);
}

// Round 2
// 120.688 us; speedup vs baseline: 1.7074x; 1.7074x over previous
//
#include <hip/hip_runtime.h>
#include <math.h>

#define EPSBN 1e-5f

constexpr int B   = 2;
constexpr int C1  = 60;           // x1 channels
constexpr int NV  = 64 * 64 * 64; // voxels per batch
constexpr int NB  = NV / 1024;    // 256 blocks per batch (4 voxels/thread, 256 thr)

// ---------------------------------------------------------------------------
// Kernel A: DWT + BN + ReLU + LL out + conv0 (1x1x1, 64->4) + channel partials
// dwt, s0 channel-last [b][voxel][4] (float4); part channel-major [b][64][NB]
// 4 voxels per thread, all accesses float4.
// ---------------------------------------------------------------------------
__global__ __launch_bounds__(256) void kA(
    const float* __restrict__ x1, const float* __restrict__ x2,
    const float* __restrict__ bn_g, const float* __restrict__ bn_b,
    const float* __restrict__ bn_m, const float* __restrict__ bn_v,
    const float* __restrict__ sg_w0, const float* __restrict__ sg_b0,
    const float* __restrict__ sg_g0, const float* __restrict__ sg_be0,
    const float* __restrict__ sg_m0, const float* __restrict__ sg_v0,
    float* __restrict__ dwt, float* __restrict__ s0,
    float* __restrict__ part, float* __restrict__ outLL)
{
    __shared__ float w0l[256];      // [r][c]
    __shared__ float cA[4], cB[4];  // s0 = relu(acc*cA + cB)
    __shared__ float dsc[4], dsh[4];
    __shared__ float wsum[64][4];

    const int tid = threadIdx.x;
    w0l[tid] = sg_w0[tid];
    if (tid < 4) {
        float sc = sg_g0[tid] * rsqrtf(sg_v0[tid] + EPSBN);
        cA[tid] = sc;
        cB[tid] = (sg_b0[tid] - sg_m0[tid]) * sc + sg_be0[tid];
        float d = bn_g[tid] * rsqrtf(bn_v[tid] + EPSBN);
        dsc[tid] = d;
        dsh[tid] = bn_b[tid] - bn_m[tid] * d;
    }
    __syncthreads();

    const int b = blockIdx.y;
    const int v = blockIdx.x * 1024 + tid * 4;   // base voxel (4-aligned in x)
    const int x = v & 63, y = (v >> 6) & 63, z = v >> 12;
    const int lane = tid & 63, wv = tid >> 6;

    // Haar DWT2 over (D,H): 4 consecutive x per thread
    const float* px2 = x2 + (size_t)b * (128 * 128 * 64);
    const size_t i00 = ((size_t)(2 * z) * 128 + 2 * y) * 64 + x;
    const float4 p00 = *(const float4*)(px2 + i00);
    const float4 p01 = *(const float4*)(px2 + i00 + 64);
    const float4 p10 = *(const float4*)(px2 + i00 + 8192);
    const float4 p11 = *(const float4*)(px2 + i00 + 8256);
    const float* q00 = (const float*)&p00; const float* q01 = (const float*)&p01;
    const float* q10 = (const float*)&p10; const float* q11 = (const float*)&p11;

    float tv[4][4];   // [vi][channel]  post-BN-ReLU dwt values
    float llv[4];
    #pragma unroll
    for (int vi = 0; vi < 4; ++vi) {
        float a = q00[vi], bb = q01[vi], c = q10[vi], d = q11[vi];
        float LL = 0.5f * (a + bb + c + d);
        float LH = 0.5f * (a + bb - c - d);
        float HL = 0.5f * (a - bb + c - d);
        float HH = 0.5f * (a - bb - c + d);
        llv[vi] = LL;
        tv[vi][0] = fmaxf(LL * dsc[0] + dsh[0], 0.f);
        tv[vi][1] = fmaxf(LH * dsc[1] + dsh[1], 0.f);
        tv[vi][2] = fmaxf(HL * dsc[2] + dsh[2], 0.f);
        tv[vi][3] = fmaxf(HH * dsc[3] + dsh[3], 0.f);
    }
    *(float4*)(outLL + (size_t)b * NV + v) = make_float4(llv[0], llv[1], llv[2], llv[3]);

    float acc[4][4] = {};   // [vi][r] conv0 accumulators
    #pragma unroll
    for (int c = 0; c < 4; ++c) {
        #pragma unroll
        for (int vi = 0; vi < 4; ++vi) {
            float t = tv[vi][c];
            #pragma unroll
            for (int r = 0; r < 4; ++r) acc[vi][r] += w0l[r * 64 + c] * t;
        }
        float rs = tv[0][c] + tv[1][c] + tv[2][c] + tv[3][c];
        #pragma unroll
        for (int off = 32; off; off >>= 1) rs += __shfl_xor(rs, off);
        if (lane == 0) wsum[c][wv] = rs;
    }

    float4* pdwt = (float4*)dwt + (size_t)b * NV + v;
    #pragma unroll
    for (int vi = 0; vi < 4; ++vi)
        pdwt[vi] = make_float4(tv[vi][0], tv[vi][1], tv[vi][2], tv[vi][3]);

    const float* px1 = x1 + (size_t)b * C1 * NV + v;
    for (int c = 0; c < C1; ++c) {
        const float4 f = *(const float4*)(px1 + (size_t)c * NV);
        const float* fv = (const float*)&f;
        #pragma unroll
        for (int vi = 0; vi < 4; ++vi) {
            #pragma unroll
            for (int r = 0; r < 4; ++r) acc[vi][r] += w0l[r * 64 + 4 + c] * fv[vi];
        }
        float rs = f.x + f.y + f.z + f.w;
        #pragma unroll
        for (int off = 32; off; off >>= 1) rs += __shfl_xor(rs, off);
        if (lane == 0) wsum[4 + c][wv] = rs;
    }

    float4* ps0 = (float4*)s0 + (size_t)b * NV + v;
    #pragma unroll
    for (int vi = 0; vi < 4; ++vi)
        ps0[vi] = make_float4(fmaxf(acc[vi][0] * cA[0] + cB[0], 0.f),
                              fmaxf(acc[vi][1] * cA[1] + cB[1], 0.f),
                              fmaxf(acc[vi][2] * cA[2] + cB[2], 0.f),
                              fmaxf(acc[vi][3] * cA[3] + cB[3], 0.f));

    __syncthreads();
    if (tid < 64) {
        float p = wsum[tid][0] + wsum[tid][1] + wsum[tid][2] + wsum[tid][3];
        part[((size_t)b * 64 + tid) * NB + blockIdx.x] = p;
    }
}

// ---------------------------------------------------------------------------
// Dilated 3x3x3 conv (dil=4, pad=4), 4->4 ch, + BN + ReLU.  4 voxels/thread.
// ---------------------------------------------------------------------------
__global__ __launch_bounds__(256) void kConv1(
    const float* __restrict__ sin_,
    const float* __restrict__ w, const float* __restrict__ bias,
    const float* __restrict__ g, const float* __restrict__ be,
    const float* __restrict__ m, const float* __restrict__ vv,
    float* __restrict__ outp)
{
    __shared__ float wl[432];
    __shared__ float cA[4], cB[4];
    const int tid = threadIdx.x;
    for (int i = tid; i < 432; i += 256) wl[i] = w[i];
    if (tid < 4) {
        float sc = g[tid] * rsqrtf(vv[tid] + EPSBN);
        cA[tid] = sc;
        cB[tid] = (bias[tid] - m[tid]) * sc + be[tid];
    }
    __syncthreads();

    const int b = blockIdx.y;
    const int v = blockIdx.x * 1024 + tid * 4;
    const int x = v & 63, y = (v >> 6) & 63, z = v >> 12;
    const float4* pin = (const float4*)sin_ + (size_t)b * NV;

    float acc[4][4] = {};
    #pragma unroll
    for (int kz = -1; kz <= 1; ++kz) {
        const int zz = z + 4 * kz;
        if ((unsigned)zz >= 64u) continue;
        #pragma unroll
        for (int ky = -1; ky <= 1; ++ky) {
            const int yy = y + 4 * ky;
            if ((unsigned)yy >= 64u) continue;
            #pragma unroll
            for (int kx = -1; kx <= 1; ++kx) {
                const int xx = x + 4 * kx;
                if ((unsigned)xx >= 64u) continue;
                const int t = (kz + 1) * 9 + (ky + 1) * 3 + (kx + 1);
                const int vt = zz * 4096 + yy * 64 + xx;
                #pragma unroll
                for (int vi = 0; vi < 4; ++vi) {
                    const float4 tap = pin[vt + vi];
                    acc[vi][0] += wl[      t] * tap.x + wl[ 27 + t] * tap.y + wl[ 54 + t] * tap.z + wl[ 81 + t] * tap.w;
                    acc[vi][1] += wl[108 + t] * tap.x + wl[135 + t] * tap.y + wl[162 + t] * tap.z + wl[189 + t] * tap.w;
                    acc[vi][2] += wl[216 + t] * tap.x + wl[243 + t] * tap.y + wl[270 + t] * tap.z + wl[297 + t] * tap.w;
                    acc[vi][3] += wl[324 + t] * tap.x + wl[351 + t] * tap.y + wl[378 + t] * tap.z + wl[405 + t] * tap.w;
                }
            }
        }
    }

    float4* po = (float4*)outp + (size_t)b * NV + v;
    #pragma unroll
    for (int vi = 0; vi < 4; ++vi)
        po[vi] = make_float4(fmaxf(acc[vi][0] * cA[0] + cB[0], 0.f),
                             fmaxf(acc[vi][1] * cA[1] + cB[1], 0.f),
                             fmaxf(acc[vi][2] * cA[2] + cB[2], 0.f),
                             fmaxf(acc[vi][3] * cA[3] + cB[3], 0.f));
}

// ---------------------------------------------------------------------------
// Pooled mean (from channel-major partials) + channel-gate MLP -> att_c
// ---------------------------------------------------------------------------
__global__ __launch_bounds__(256) void kMLP(
    const float* __restrict__ part,
    const float* __restrict__ cg_w1, const float* __restrict__ cg_b1,
    const float* __restrict__ cg_bng, const float* __restrict__ cg_bnb,
    const float* __restrict__ cg_bnm, const float* __restrict__ cg_bnv,
    const float* __restrict__ cg_w2, const float* __restrict__ cg_b2,
    float* __restrict__ att_c)
{
    const int b = blockIdx.x;
    const int tid = threadIdx.x;
    __shared__ float pooled[64];
    __shared__ float h[4];

    const int c = tid >> 2, q = tid & 3;
    const float4* pp = (const float4*)(part + ((size_t)b * 64 + c) * NB + q * 64);
    float sm = 0.f;
    #pragma unroll
    for (int i = 0; i < 16; ++i) { float4 f = pp[i]; sm += f.x + f.y + f.z + f.w; }
    sm += __shfl_xor(sm, 1);
    sm += __shfl_xor(sm, 2);
    if (q == 0) pooled[c] = sm * (1.0f / NV);
    __syncthreads();
    if (tid < 4) {
        float a = cg_b1[tid];
        for (int cc = 0; cc < 64; ++cc) a += pooled[cc] * cg_w1[tid * 64 + cc];
        float sc = cg_bng[tid] * rsqrtf(cg_bnv[tid] + EPSBN);
        h[tid] = fmaxf((a - cg_bnm[tid]) * sc + cg_bnb[tid], 0.f);
    }
    __syncthreads();
    if (tid < 64) {
        float a = cg_b2[tid];
        #pragma unroll
        for (int r = 0; r < 4; ++r) a += h[r] * cg_w2[tid * 4 + r];
        att_c[b * 64 + tid] = a;
    }
}

// ---------------------------------------------------------------------------
// Final fused: conv2(dil=4)+BN+ReLU -> conv3(1x1x1)-> att_s ->
//              out = feat * (1 + sigmoid(att_c + att_s)).   4 voxels/thread.
// sigmoid(a+b) = 1 / (1 + e^{-a} e^{-b})
// ---------------------------------------------------------------------------
__global__ __launch_bounds__(256) void kF(
    const float* __restrict__ x1,
    const float* __restrict__ dwt,
    const float* __restrict__ s1,
    const float* __restrict__ w, const float* __restrict__ bias,
    const float* __restrict__ g, const float* __restrict__ be,
    const float* __restrict__ m, const float* __restrict__ vv,
    const float* __restrict__ w3, const float* __restrict__ b3,
    const float* __restrict__ att_c,
    float* __restrict__ out0)
{
    __shared__ float wl[432];
    __shared__ float cA[4], cB[4], w3l[4], b3l;
    __shared__ float ec[64];
    const int tid = threadIdx.x;
    const int b = blockIdx.y;
    for (int i = tid; i < 432; i += 256) wl[i] = w[i];
    if (tid < 4) {
        float sc = g[tid] * rsqrtf(vv[tid] + EPSBN);
        cA[tid] = sc;
        cB[tid] = (bias[tid] - m[tid]) * sc + be[tid];
        w3l[tid] = w3[tid];
    }
    if (tid == 0) b3l = b3[0];
    if (tid < 64) ec[tid] = __expf(-att_c[b * 64 + tid]);
    __syncthreads();

    const int v = blockIdx.x * 1024 + tid * 4;
    const int x = v & 63, y = (v >> 6) & 63, z = v >> 12;
    const float4* pin = (const float4*)s1 + (size_t)b * NV;

    float acc[4][4] = {};
    #pragma unroll
    for (int kz = -1; kz <= 1; ++kz) {
        const int zz = z + 4 * kz;
        if ((unsigned)zz >= 64u) continue;
        #pragma unroll
        for (int ky = -1; ky <= 1; ++ky) {
            const int yy = y + 4 * ky;
            if ((unsigned)yy >= 64u) continue;
            #pragma unroll
            for (int kx = -1; kx <= 1; ++kx) {
                const int xx = x + 4 * kx;
                if ((unsigned)xx >= 64u) continue;
                const int t = (kz + 1) * 9 + (ky + 1) * 3 + (kx + 1);
                const int vt = zz * 4096 + yy * 64 + xx;
                #pragma unroll
                for (int vi = 0; vi < 4; ++vi) {
                    const float4 tap = pin[vt + vi];
                    acc[vi][0] += wl[      t] * tap.x + wl[ 27 + t] * tap.y + wl[ 54 + t] * tap.z + wl[ 81 + t] * tap.w;
                    acc[vi][1] += wl[108 + t] * tap.x + wl[135 + t] * tap.y + wl[162 + t] * tap.z + wl[189 + t] * tap.w;
                    acc[vi][2] += wl[216 + t] * tap.x + wl[243 + t] * tap.y + wl[270 + t] * tap.z + wl[297 + t] * tap.w;
                    acc[vi][3] += wl[324 + t] * tap.x + wl[351 + t] * tap.y + wl[378 + t] * tap.z + wl[405 + t] * tap.w;
                }
            }
        }
    }

    float eas[4];
    #pragma unroll
    for (int vi = 0; vi < 4; ++vi) {
        float r0 = fmaxf(acc[vi][0] * cA[0] + cB[0], 0.f);
        float r1 = fmaxf(acc[vi][1] * cA[1] + cB[1], 0.f);
        float r2 = fmaxf(acc[vi][2] * cA[2] + cB[2], 0.f);
        float r3 = fmaxf(acc[vi][3] * cA[3] + cB[3], 0.f);
        float as = b3l + w3l[0] * r0 + w3l[1] * r1 + w3l[2] * r2 + w3l[3] * r3;
        eas[vi] = __expf(-as);
    }

    // dwt channels (0..3): channel-last -> channel-major transpose in regs
    float dv[4][4];
    const float4* pdwt = (const float4*)dwt + (size_t)b * NV + v;
    #pragma unroll
    for (int vi = 0; vi < 4; ++vi) {
        const float4 dq = pdwt[vi];
        dv[vi][0] = dq.x; dv[vi][1] = dq.y; dv[vi][2] = dq.z; dv[vi][3] = dq.w;
    }
    float* po = out0 + (size_t)b * 64 * NV + v;
    #pragma unroll
    for (int c = 0; c < 4; ++c) {
        float e = ec[c];
        float4 o;
        o.x = dv[0][c] * (1.f + __builtin_amdgcn_rcpf(1.f + e * eas[0]));
        o.y = dv[1][c] * (1.f + __builtin_amdgcn_rcpf(1.f + e * eas[1]));
        o.z = dv[2][c] * (1.f + __builtin_amdgcn_rcpf(1.f + e * eas[2]));
        o.w = dv[3][c] * (1.f + __builtin_amdgcn_rcpf(1.f + e * eas[3]));
        *(float4*)(po + (size_t)c * NV) = o;
    }
    const float* px1 = x1 + (size_t)b * C1 * NV + v;
    for (int c = 0; c < C1; ++c) {
        const float4 f = *(const float4*)(px1 + (size_t)c * NV);
        const float e = ec[4 + c];
        float4 o;
        o.x = f.x * (1.f + __builtin_amdgcn_rcpf(1.f + e * eas[0]));
        o.y = f.y * (1.f + __builtin_amdgcn_rcpf(1.f + e * eas[1]));
        o.z = f.z * (1.f + __builtin_amdgcn_rcpf(1.f + e * eas[2]));
        o.w = f.w * (1.f + __builtin_amdgcn_rcpf(1.f + e * eas[3]));
        *(float4*)(po + (size_t)(4 + c) * NV) = o;
    }
}

// ---------------------------------------------------------------------------
extern "C" void kernel_launch(void* const* d_in, const int* in_sizes, int n_in,
                              void* d_out, int out_size, void* d_ws, size_t ws_size,
                              hipStream_t stream)
{
    const float* x1 = (const float*)d_in[0];
    const float* x2 = (const float*)d_in[1];
    const float* bn_g = (const float*)d_in[2];
    const float* bn_b = (const float*)d_in[3];
    const float* bn_m = (const float*)d_in[4];
    const float* bn_v = (const float*)d_in[5];
    const float* cg_w1 = (const float*)d_in[6];
    const float* cg_b1 = (const float*)d_in[7];
    const float* cg_bng = (const float*)d_in[8];
    const float* cg_bnb = (const float*)d_in[9];
    const float* cg_bnm = (const float*)d_in[10];
    const float* cg_bnv = (const float*)d_in[11];
    const float* cg_w2 = (const float*)d_in[12];
    const float* cg_b2 = (const float*)d_in[13];
    const float* sg_w0 = (const float*)d_in[14];
    const float* sg_b0 = (const float*)d_in[15];
    const float* sg_g0 = (const float*)d_in[16];
    const float* sg_be0 = (const float*)d_in[17];
    const float* sg_m0 = (const float*)d_in[18];
    const float* sg_v0 = (const float*)d_in[19];
    const float* sg_w1 = (const float*)d_in[20];
    const float* sg_b1 = (const float*)d_in[21];
    const float* sg_g1 = (const float*)d_in[22];
    const float* sg_be1 = (const float*)d_in[23];
    const float* sg_m1 = (const float*)d_in[24];
    const float* sg_v1 = (const float*)d_in[25];
    const float* sg_w2 = (const float*)d_in[26];
    const float* sg_b2 = (const float*)d_in[27];
    const float* sg_g2 = (const float*)d_in[28];
    const float* sg_be2 = (const float*)d_in[29];
    const float* sg_m2 = (const float*)d_in[30];
    const float* sg_v2 = (const float*)d_in[31];
    const float* sg_w3 = (const float*)d_in[32];
    const float* sg_b3 = (const float*)d_in[33];

    float* ws = (float*)d_ws;
    float* dwt  = ws;                 // B*NV*4 = 2,097,152 floats
    float* s0   = ws + 2097152;       // 2,097,152
    float* s1   = ws + 4194304;       // 2,097,152
    float* part = ws + 6291456;       // B*64*NB = 32,768
    float* attc = ws + 6324224;       // 128

    float* out0  = (float*)d_out;
    float* outLL = out0 + (size_t)B * 64 * NV;

    dim3 grid(NB, B), blk(256);
    kA<<<grid, blk, 0, stream>>>(x1, x2, bn_g, bn_b, bn_m, bn_v,
                                 sg_w0, sg_b0, sg_g0, sg_be0, sg_m0, sg_v0,
                                 dwt, s0, part, outLL);
    kConv1<<<grid, blk, 0, stream>>>(s0, sg_w1, sg_b1, sg_g1, sg_be1, sg_m1, sg_v1, s1);
    kMLP<<<dim3(B), blk, 0, stream>>>(part, cg_w1, cg_b1, cg_bng, cg_bnb, cg_bnm, cg_bnv,
                                      cg_w2, cg_b2, attc);
    kF<<<grid, blk, 0, stream>>>(x1, dwt, s1, sg_w2, sg_b2, sg_g2, sg_be2, sg_m2, sg_v2,
                                 sg_w3, sg_b3, attc, out0);
}

// Round 3
// 118.000 us; speedup vs baseline: 1.7463x; 1.0228x over previous
//
#include <hip/hip_runtime.h>
#include <math.h>

#define EPSBN 1e-5f

constexpr int B   = 2;
constexpr int C1  = 60;           // x1 channels
constexpr int NV  = 64 * 64 * 64; // voxels per batch
constexpr int NBa = NV / 512;     // 512 blocks/batch (2 voxels/thread, 256 thr)

// ---------------------------------------------------------------------------
// Kernel A: DWT + BN + ReLU + LL out + conv0 (1x1x1, 64->4) + channel partials
// dwtM channel-major [b][4][NV]; s0 channel-last [b][voxel][4] (float4 taps)
// part channel-major [b][64][NBa].  2 voxels/thread.
// ---------------------------------------------------------------------------
__global__ __launch_bounds__(256) void kA(
    const float* __restrict__ x1, const float* __restrict__ x2,
    const float* __restrict__ bn_g, const float* __restrict__ bn_b,
    const float* __restrict__ bn_m, const float* __restrict__ bn_v,
    const float* __restrict__ sg_w0, const float* __restrict__ sg_b0,
    const float* __restrict__ sg_g0, const float* __restrict__ sg_be0,
    const float* __restrict__ sg_m0, const float* __restrict__ sg_v0,
    float* __restrict__ dwtM, float* __restrict__ s0,
    float* __restrict__ part, float* __restrict__ outLL)
{
    __shared__ float w0l[256];      // [r][c]
    __shared__ float cA[4], cB[4];
    __shared__ float dsc[4], dsh[4];
    __shared__ float wsum[64][4];

    const int tid = threadIdx.x;
    w0l[tid] = sg_w0[tid];
    if (tid < 4) {
        float sc = sg_g0[tid] * rsqrtf(sg_v0[tid] + EPSBN);
        cA[tid] = sc;
        cB[tid] = (sg_b0[tid] - sg_m0[tid]) * sc + sg_be0[tid];
        float d = bn_g[tid] * rsqrtf(bn_v[tid] + EPSBN);
        dsc[tid] = d;
        dsh[tid] = bn_b[tid] - bn_m[tid] * d;
    }
    __syncthreads();

    const int b = blockIdx.y;
    const int v = blockIdx.x * 512 + tid * 2;  // even x
    const int x = v & 63, y = (v >> 6) & 63, z = v >> 12;
    const int lane = tid & 63, wv = tid >> 6;

    // Haar DWT2 over (D,H)
    const float* px2 = x2 + (size_t)b * (128 * 128 * 64);
    const size_t i00 = ((size_t)(2 * z) * 128 + 2 * y) * 64 + x;
    const float2 p00 = *(const float2*)(px2 + i00);
    const float2 p01 = *(const float2*)(px2 + i00 + 64);
    const float2 p10 = *(const float2*)(px2 + i00 + 8192);
    const float2 p11 = *(const float2*)(px2 + i00 + 8256);
    const float* q00 = (const float*)&p00; const float* q01 = (const float*)&p01;
    const float* q10 = (const float*)&p10; const float* q11 = (const float*)&p11;

    float tv[2][4], llv[2];
    #pragma unroll
    for (int vi = 0; vi < 2; ++vi) {
        float a = q00[vi], bb = q01[vi], c = q10[vi], d = q11[vi];
        float LL = 0.5f * (a + bb + c + d);
        float LH = 0.5f * (a + bb - c - d);
        float HL = 0.5f * (a - bb + c - d);
        float HH = 0.5f * (a - bb - c + d);
        llv[vi] = LL;
        tv[vi][0] = fmaxf(LL * dsc[0] + dsh[0], 0.f);
        tv[vi][1] = fmaxf(LH * dsc[1] + dsh[1], 0.f);
        tv[vi][2] = fmaxf(HL * dsc[2] + dsh[2], 0.f);
        tv[vi][3] = fmaxf(HH * dsc[3] + dsh[3], 0.f);
    }
    *(float2*)(outLL + (size_t)b * NV + v) = make_float2(llv[0], llv[1]);

    float acc[2][4] = {};
    #pragma unroll
    for (int c = 0; c < 4; ++c) {
        #pragma unroll
        for (int vi = 0; vi < 2; ++vi) {
            float t = tv[vi][c];
            #pragma unroll
            for (int r = 0; r < 4; ++r) acc[vi][r] += w0l[r * 64 + c] * t;
        }
        float rs = tv[0][c] + tv[1][c];
        #pragma unroll
        for (int off = 32; off; off >>= 1) rs += __shfl_xor(rs, off);
        if (lane == 0) wsum[c][wv] = rs;
        // channel-major dwt store
        *(float2*)(dwtM + ((size_t)b * 4 + c) * NV + v) = make_float2(tv[0][c], tv[1][c]);
    }

    const float* px1 = x1 + (size_t)b * C1 * NV + v;
    for (int c = 0; c < C1; ++c) {
        const float2 f = *(const float2*)(px1 + (size_t)c * NV);
        #pragma unroll
        for (int r = 0; r < 4; ++r) {
            acc[0][r] += w0l[r * 64 + 4 + c] * f.x;
            acc[1][r] += w0l[r * 64 + 4 + c] * f.y;
        }
        float rs = f.x + f.y;
        #pragma unroll
        for (int off = 32; off; off >>= 1) rs += __shfl_xor(rs, off);
        if (lane == 0) wsum[4 + c][wv] = rs;
    }

    float4* ps0 = (float4*)s0 + (size_t)b * NV + v;
    #pragma unroll
    for (int vi = 0; vi < 2; ++vi)
        ps0[vi] = make_float4(fmaxf(acc[vi][0] * cA[0] + cB[0], 0.f),
                              fmaxf(acc[vi][1] * cA[1] + cB[1], 0.f),
                              fmaxf(acc[vi][2] * cA[2] + cB[2], 0.f),
                              fmaxf(acc[vi][3] * cA[3] + cB[3], 0.f));

    __syncthreads();
    if (tid < 64) {
        float p = wsum[tid][0] + wsum[tid][1] + wsum[tid][2] + wsum[tid][3];
        part[((size_t)b * 64 + tid) * NBa + blockIdx.x] = p;
    }
}

// ---------------------------------------------------------------------------
// kConv1: dilated conv1 + BN + ReLU (2 voxels/thread).
// Extra block (blockIdx.x == NBa) runs the channel-gate MLP -> ec = e^{-att_c}.
// ---------------------------------------------------------------------------
__global__ __launch_bounds__(256) void kConv1(
    const float* __restrict__ sin_,
    const float* __restrict__ w, const float* __restrict__ bias,
    const float* __restrict__ g, const float* __restrict__ be,
    const float* __restrict__ m, const float* __restrict__ vv,
    const float* __restrict__ part,
    const float* __restrict__ cg_w1, const float* __restrict__ cg_b1,
    const float* __restrict__ cg_bng, const float* __restrict__ cg_bnb,
    const float* __restrict__ cg_bnm, const float* __restrict__ cg_bnv,
    const float* __restrict__ cg_w2, const float* __restrict__ cg_b2,
    float* __restrict__ ec,
    float* __restrict__ outp)
{
    const int tid = threadIdx.x;
    const int b = blockIdx.y;

    if (blockIdx.x == NBa) {   // ---- channel-gate MLP ----
        __shared__ float pooled[64];
        __shared__ float h[4];
        const int c = tid >> 2, q = tid & 3;
        const float4* pp = (const float4*)(part + ((size_t)b * 64 + c) * NBa + q * 128);
        float sm = 0.f;
        #pragma unroll
        for (int i = 0; i < 32; ++i) { float4 f = pp[i]; sm += f.x + f.y + f.z + f.w; }
        sm += __shfl_xor(sm, 1);
        sm += __shfl_xor(sm, 2);
        if (q == 0) pooled[c] = sm * (1.0f / NV);
        __syncthreads();
        if (tid < 4) {
            float a = cg_b1[tid];
            for (int cc = 0; cc < 64; ++cc) a += pooled[cc] * cg_w1[tid * 64 + cc];
            float sc = cg_bng[tid] * rsqrtf(cg_bnv[tid] + EPSBN);
            h[tid] = fmaxf((a - cg_bnm[tid]) * sc + cg_bnb[tid], 0.f);
        }
        __syncthreads();
        if (tid < 64) {
            float a = cg_b2[tid];
            #pragma unroll
            for (int r = 0; r < 4; ++r) a += h[r] * cg_w2[tid * 4 + r];
            ec[b * 64 + tid] = __expf(-a);
        }
        return;
    }

    __shared__ float wl[432];
    __shared__ float cA[4], cB[4];
    for (int i = tid; i < 432; i += 256) wl[i] = w[i];
    if (tid < 4) {
        float sc = g[tid] * rsqrtf(vv[tid] + EPSBN);
        cA[tid] = sc;
        cB[tid] = (bias[tid] - m[tid]) * sc + be[tid];
    }
    __syncthreads();

    const int v = blockIdx.x * 512 + tid * 2;
    const int x = v & 63, y = (v >> 6) & 63, z = v >> 12;
    const float4* pin = (const float4*)sin_ + (size_t)b * NV;

    float acc[2][4] = {};
    #pragma unroll
    for (int kz = -1; kz <= 1; ++kz) {
        const int zz = z + 4 * kz;
        if ((unsigned)zz >= 64u) continue;
        #pragma unroll
        for (int ky = -1; ky <= 1; ++ky) {
            const int yy = y + 4 * ky;
            if ((unsigned)yy >= 64u) continue;
            #pragma unroll
            for (int kx = -1; kx <= 1; ++kx) {
                const int xx = x + 4 * kx;       // even, so xx+1 in-bounds iff xx is
                if ((unsigned)xx >= 64u) continue;
                const int t = (kz + 1) * 9 + (ky + 1) * 3 + (kx + 1);
                const int vt = zz * 4096 + yy * 64 + xx;
                #pragma unroll
                for (int vi = 0; vi < 2; ++vi) {
                    const float4 tap = pin[vt + vi];
                    acc[vi][0] += wl[      t] * tap.x + wl[ 27 + t] * tap.y + wl[ 54 + t] * tap.z + wl[ 81 + t] * tap.w;
                    acc[vi][1] += wl[108 + t] * tap.x + wl[135 + t] * tap.y + wl[162 + t] * tap.z + wl[189 + t] * tap.w;
                    acc[vi][2] += wl[216 + t] * tap.x + wl[243 + t] * tap.y + wl[270 + t] * tap.z + wl[297 + t] * tap.w;
                    acc[vi][3] += wl[324 + t] * tap.x + wl[351 + t] * tap.y + wl[378 + t] * tap.z + wl[405 + t] * tap.w;
                }
            }
        }
    }

    float4* po = (float4*)outp + (size_t)b * NV + v;
    #pragma unroll
    for (int vi = 0; vi < 2; ++vi)
        po[vi] = make_float4(fmaxf(acc[vi][0] * cA[0] + cB[0], 0.f),
                             fmaxf(acc[vi][1] * cA[1] + cB[1], 0.f),
                             fmaxf(acc[vi][2] * cA[2] + cB[2], 0.f),
                             fmaxf(acc[vi][3] * cA[3] + cB[3], 0.f));
}

// ---------------------------------------------------------------------------
// kConv2: dilated conv2 + BN + ReLU + conv3 (1x1x1) -> es = e^{-att_s}
// ---------------------------------------------------------------------------
__global__ __launch_bounds__(256) void kConv2(
    const float* __restrict__ sin_,
    const float* __restrict__ w, const float* __restrict__ bias,
    const float* __restrict__ g, const float* __restrict__ be,
    const float* __restrict__ m, const float* __restrict__ vv,
    const float* __restrict__ w3, const float* __restrict__ b3,
    float* __restrict__ es)
{
    __shared__ float wl[432];
    __shared__ float cA[4], cB[4], w3l[4], b3l;
    const int tid = threadIdx.x;
    for (int i = tid; i < 432; i += 256) wl[i] = w[i];
    if (tid < 4) {
        float sc = g[tid] * rsqrtf(vv[tid] + EPSBN);
        cA[tid] = sc;
        cB[tid] = (bias[tid] - m[tid]) * sc + be[tid];
        w3l[tid] = w3[tid];
    }
    if (tid == 0) b3l = b3[0];
    __syncthreads();

    const int b = blockIdx.y;
    const int v = blockIdx.x * 512 + tid * 2;
    const int x = v & 63, y = (v >> 6) & 63, z = v >> 12;
    const float4* pin = (const float4*)sin_ + (size_t)b * NV;

    float acc[2][4] = {};
    #pragma unroll
    for (int kz = -1; kz <= 1; ++kz) {
        const int zz = z + 4 * kz;
        if ((unsigned)zz >= 64u) continue;
        #pragma unroll
        for (int ky = -1; ky <= 1; ++ky) {
            const int yy = y + 4 * ky;
            if ((unsigned)yy >= 64u) continue;
            #pragma unroll
            for (int kx = -1; kx <= 1; ++kx) {
                const int xx = x + 4 * kx;
                if ((unsigned)xx >= 64u) continue;
                const int t = (kz + 1) * 9 + (ky + 1) * 3 + (kx + 1);
                const int vt = zz * 4096 + yy * 64 + xx;
                #pragma unroll
                for (int vi = 0; vi < 2; ++vi) {
                    const float4 tap = pin[vt + vi];
                    acc[vi][0] += wl[      t] * tap.x + wl[ 27 + t] * tap.y + wl[ 54 + t] * tap.z + wl[ 81 + t] * tap.w;
                    acc[vi][1] += wl[108 + t] * tap.x + wl[135 + t] * tap.y + wl[162 + t] * tap.z + wl[189 + t] * tap.w;
                    acc[vi][2] += wl[216 + t] * tap.x + wl[243 + t] * tap.y + wl[270 + t] * tap.z + wl[297 + t] * tap.w;
                    acc[vi][3] += wl[324 + t] * tap.x + wl[351 + t] * tap.y + wl[378 + t] * tap.z + wl[405 + t] * tap.w;
                }
            }
        }
    }

    float ev[2];
    #pragma unroll
    for (int vi = 0; vi < 2; ++vi) {
        float r0 = fmaxf(acc[vi][0] * cA[0] + cB[0], 0.f);
        float r1 = fmaxf(acc[vi][1] * cA[1] + cB[1], 0.f);
        float r2 = fmaxf(acc[vi][2] * cA[2] + cB[2], 0.f);
        float r3 = fmaxf(acc[vi][3] * cA[3] + cB[3], 0.f);
        ev[vi] = __expf(-(b3l + w3l[0] * r0 + w3l[1] * r1 + w3l[2] * r2 + w3l[3] * r3));
    }
    *(float2*)(es + (size_t)b * NV + v) = make_float2(ev[0], ev[1]);
}

// ---------------------------------------------------------------------------
// kMul: pure streaming.  out[idx] = in[idx] * (1 + 1/(1 + ec[b,c]*es[b,v]))
// idx enumerates (b, c, voxel-quad); c is wave-uniform.
// ---------------------------------------------------------------------------
__global__ __launch_bounds__(256) void kMul(
    const float* __restrict__ x1,
    const float* __restrict__ dwtM,
    const float* __restrict__ es,
    const float* __restrict__ ec,
    float* __restrict__ out0)
{
    const int i0 = blockIdx.x * 256 + threadIdx.x;   // [0, 524288)
    #pragma unroll 4
    for (int it = 0; it < 16; ++it) {
        const size_t idx = (size_t)i0 + (size_t)it * 524288;  // float4 index
        const int b  = (int)(idx >> 22);
        const int r  = (int)(idx & 4194303);
        const int c  = r >> 16;
        const int vq = r & 65535;
        const float* base = (c < 4)
            ? dwtM + ((size_t)b * 4 + c) * NV
            : x1   + ((size_t)b * C1 + (c - 4)) * NV;
        const float4 in4 = *(const float4*)(base + (size_t)vq * 4);
        const float4 es4 = ((const float4*)(es + (size_t)b * NV))[vq];
        const float  e   = ec[(b << 6) + c];
        float4 o;
        o.x = in4.x * (1.f + __builtin_amdgcn_rcpf(1.f + e * es4.x));
        o.y = in4.y * (1.f + __builtin_amdgcn_rcpf(1.f + e * es4.y));
        o.z = in4.z * (1.f + __builtin_amdgcn_rcpf(1.f + e * es4.z));
        o.w = in4.w * (1.f + __builtin_amdgcn_rcpf(1.f + e * es4.w));
        ((float4*)out0)[idx] = o;
    }
}

// ---------------------------------------------------------------------------
extern "C" void kernel_launch(void* const* d_in, const int* in_sizes, int n_in,
                              void* d_out, int out_size, void* d_ws, size_t ws_size,
                              hipStream_t stream)
{
    const float* x1 = (const float*)d_in[0];
    const float* x2 = (const float*)d_in[1];
    const float* bn_g = (const float*)d_in[2];
    const float* bn_b = (const float*)d_in[3];
    const float* bn_m = (const float*)d_in[4];
    const float* bn_v = (const float*)d_in[5];
    const float* cg_w1 = (const float*)d_in[6];
    const float* cg_b1 = (const float*)d_in[7];
    const float* cg_bng = (const float*)d_in[8];
    const float* cg_bnb = (const float*)d_in[9];
    const float* cg_bnm = (const float*)d_in[10];
    const float* cg_bnv = (const float*)d_in[11];
    const float* cg_w2 = (const float*)d_in[12];
    const float* cg_b2 = (const float*)d_in[13];
    const float* sg_w0 = (const float*)d_in[14];
    const float* sg_b0 = (const float*)d_in[15];
    const float* sg_g0 = (const float*)d_in[16];
    const float* sg_be0 = (const float*)d_in[17];
    const float* sg_m0 = (const float*)d_in[18];
    const float* sg_v0 = (const float*)d_in[19];
    const float* sg_w1 = (const float*)d_in[20];
    const float* sg_b1 = (const float*)d_in[21];
    const float* sg_g1 = (const float*)d_in[22];
    const float* sg_be1 = (const float*)d_in[23];
    const float* sg_m1 = (const float*)d_in[24];
    const float* sg_v1 = (const float*)d_in[25];
    const float* sg_w2 = (const float*)d_in[26];
    const float* sg_b2 = (const float*)d_in[27];
    const float* sg_g2 = (const float*)d_in[28];
    const float* sg_be2 = (const float*)d_in[29];
    const float* sg_m2 = (const float*)d_in[30];
    const float* sg_v2 = (const float*)d_in[31];
    const float* sg_w3 = (const float*)d_in[32];
    const float* sg_b3 = (const float*)d_in[33];

    float* ws = (float*)d_ws;
    float* dwtM = ws;                 // 2*4*NV   = 2,097,152
    float* s0   = ws + 2097152;       //            2,097,152
    float* s1   = ws + 4194304;       //            2,097,152
    float* es   = ws + 6291456;       // B*NV     =   524,288
    float* part = ws + 6815744;       // B*64*NBa =    65,536
    float* ec   = ws + 6881280;       //                  128

    float* out0  = (float*)d_out;
    float* outLL = out0 + (size_t)B * 64 * NV;

    dim3 blk(256);
    kA<<<dim3(NBa, B), blk, 0, stream>>>(x1, x2, bn_g, bn_b, bn_m, bn_v,
                                         sg_w0, sg_b0, sg_g0, sg_be0, sg_m0, sg_v0,
                                         dwtM, s0, part, outLL);
    kConv1<<<dim3(NBa + 1, B), blk, 0, stream>>>(s0, sg_w1, sg_b1, sg_g1, sg_be1, sg_m1, sg_v1,
                                                 part, cg_w1, cg_b1, cg_bng, cg_bnb, cg_bnm, cg_bnv,
                                                 cg_w2, cg_b2, ec, s1);
    kConv2<<<dim3(NBa, B), blk, 0, stream>>>(s1, sg_w2, sg_b2, sg_g2, sg_be2, sg_m2, sg_v2,
                                             sg_w3, sg_b3, es);
    kMul<<<dim3(2048), blk, 0, stream>>>(x1, dwtM, es, ec, out0);
}

// Round 5
// 108.239 us; speedup vs baseline: 1.9037x; 1.0902x over previous
//
#include <hip/hip_runtime.h>
#include <math.h>

#define EPSBN 1e-5f

typedef float f32x2 __attribute__((ext_vector_type(2)));
typedef float f32x4 __attribute__((ext_vector_type(4)));

constexpr int B   = 2;
constexpr int C1  = 60;           // x1 channels
constexpr int NV  = 64 * 64 * 64; // voxels per batch
constexpr int NBa = NV / 512;     // 512 blocks/batch (2 voxels/thread, 256 thr)

// ---------------------------------------------------------------------------
// Kernel A: DWT + BN + ReLU + LL out + conv0 (1x1x1, 64->4) + channel partials
// dwtM channel-major [b][4][NV]; s0 channel-last [b][voxel][4]
// part channel-major [b][64][NBa].  2 voxels/thread.
// Weights via uniform global reads (scalar cache); quad-shuffle + LDS partials.
// ---------------------------------------------------------------------------
__global__ __launch_bounds__(256) void kA(
    const float* __restrict__ x1, const float* __restrict__ x2,
    const float* __restrict__ bn_g, const float* __restrict__ bn_b,
    const float* __restrict__ bn_m, const float* __restrict__ bn_v,
    const float* __restrict__ sg_w0, const float* __restrict__ sg_b0,
    const float* __restrict__ sg_g0, const float* __restrict__ sg_be0,
    const float* __restrict__ sg_m0, const float* __restrict__ sg_v0,
    float* __restrict__ dwtM, float* __restrict__ s0,
    float* __restrict__ part, float* __restrict__ outLL)
{
    __shared__ float wsumq[64][65];   // [channel][quad]  (pad 65 vs bank conflicts)

    const int tid = threadIdx.x;
    const int qid = tid >> 2;

    // per-thread BN constants (registers, no LDS)
    float dsc[4], dsh[4], c0A[4], c0B[4];
    #pragma unroll
    for (int r = 0; r < 4; ++r) {
        float d = bn_g[r] * rsqrtf(bn_v[r] + EPSBN);
        dsc[r] = d; dsh[r] = bn_b[r] - bn_m[r] * d;
        float sc = sg_g0[r] * rsqrtf(sg_v0[r] + EPSBN);
        c0A[r] = sc; c0B[r] = (sg_b0[r] - sg_m0[r]) * sc + sg_be0[r];
    }

    const int b = blockIdx.y;
    const int v = blockIdx.x * 512 + tid * 2;  // even x
    const int x = v & 63, y = (v >> 6) & 63, z = v >> 12;

    // Haar DWT2 over (D,H)
    const float* px2 = x2 + (size_t)b * (128 * 128 * 64);
    const size_t i00 = ((size_t)(2 * z) * 128 + 2 * y) * 64 + x;
    const float2 p00 = *(const float2*)(px2 + i00);
    const float2 p01 = *(const float2*)(px2 + i00 + 64);
    const float2 p10 = *(const float2*)(px2 + i00 + 8192);
    const float2 p11 = *(const float2*)(px2 + i00 + 8256);
    const float* q00 = (const float*)&p00; const float* q01 = (const float*)&p01;
    const float* q10 = (const float*)&p10; const float* q11 = (const float*)&p11;

    float tv[2][4], llv[2];
    #pragma unroll
    for (int vi = 0; vi < 2; ++vi) {
        float a = q00[vi], bb = q01[vi], c = q10[vi], d = q11[vi];
        float LL = 0.5f * (a + bb + c + d);
        float LH = 0.5f * (a + bb - c - d);
        float HL = 0.5f * (a - bb + c - d);
        float HH = 0.5f * (a - bb - c + d);
        llv[vi] = LL;
        tv[vi][0] = fmaxf(LL * dsc[0] + dsh[0], 0.f);
        tv[vi][1] = fmaxf(LH * dsc[1] + dsh[1], 0.f);
        tv[vi][2] = fmaxf(HL * dsc[2] + dsh[2], 0.f);
        tv[vi][3] = fmaxf(HH * dsc[3] + dsh[3], 0.f);
    }
    {
        f32x2 ll2 = { llv[0], llv[1] };
        __builtin_nontemporal_store(ll2, (f32x2*)(outLL + (size_t)b * NV + v));
    }

    float acc[2][4] = {};
    #pragma unroll
    for (int c = 0; c < 4; ++c) {
        #pragma unroll
        for (int vi = 0; vi < 2; ++vi) {
            float t = tv[vi][c];
            #pragma unroll
            for (int r = 0; r < 4; ++r) acc[vi][r] += sg_w0[r * 64 + c] * t;
        }
        float rs = tv[0][c] + tv[1][c];
        rs += __shfl_xor(rs, 1);
        rs += __shfl_xor(rs, 2);
        if ((tid & 3) == 0) wsumq[c][qid] = rs;
        *(float2*)(dwtM + ((size_t)b * 4 + c) * NV + v) = make_float2(tv[0][c], tv[1][c]);
    }

    const float* px1 = x1 + (size_t)b * C1 * NV + v;
    #pragma unroll 2
    for (int c = 0; c < C1; ++c) {
        const float2 f = *(const float2*)(px1 + (size_t)c * NV);
        #pragma unroll
        for (int r = 0; r < 4; ++r) {
            const float w = sg_w0[r * 64 + 4 + c];   // uniform -> s_load
            acc[0][r] += w * f.x;
            acc[1][r] += w * f.y;
        }
        float rs = f.x + f.y;
        rs += __shfl_xor(rs, 1);
        rs += __shfl_xor(rs, 2);
        if ((tid & 3) == 0) wsumq[4 + c][qid] = rs;
    }

    float4* ps0 = (float4*)s0 + (size_t)b * NV + v;
    #pragma unroll
    for (int vi = 0; vi < 2; ++vi)
        ps0[vi] = make_float4(fmaxf(acc[vi][0] * c0A[0] + c0B[0], 0.f),
                              fmaxf(acc[vi][1] * c0A[1] + c0B[1], 0.f),
                              fmaxf(acc[vi][2] * c0A[2] + c0B[2], 0.f),
                              fmaxf(acc[vi][3] * c0A[3] + c0B[3], 0.f));

    __syncthreads();
    if (tid < 64) {
        const float* rowp = &wsumq[tid][0];
        float p = 0.f;
        #pragma unroll
        for (int i = 0; i < 64; ++i) p += rowp[i];
        part[((size_t)b * 64 + tid) * NBa + blockIdx.x] = p;
    }
}

// ---------------------------------------------------------------------------
// kConv1: dilated conv1 + BN + ReLU (2 voxels/thread).
// Weights staged as float4 [tap][out_r] -> ds_read_b128 per tap/row.
// Extra block (blockIdx.x == NBa) runs the channel-gate MLP -> ec = e^{-att_c}.
// ---------------------------------------------------------------------------
__global__ __launch_bounds__(256) void kConv1(
    const float* __restrict__ sin_,
    const float* __restrict__ w, const float* __restrict__ bias,
    const float* __restrict__ g, const float* __restrict__ be,
    const float* __restrict__ m, const float* __restrict__ vv,
    const float* __restrict__ part,
    const float* __restrict__ cg_w1, const float* __restrict__ cg_b1,
    const float* __restrict__ cg_bng, const float* __restrict__ cg_bnb,
    const float* __restrict__ cg_bnm, const float* __restrict__ cg_bnv,
    const float* __restrict__ cg_w2, const float* __restrict__ cg_b2,
    float* __restrict__ ec,
    float* __restrict__ outp)
{
    const int tid = threadIdx.x;
    const int b = blockIdx.y;

    if (blockIdx.x == NBa) {   // ---- channel-gate MLP ----
        __shared__ float pooled[64];
        __shared__ float h[4];
        const int c = tid >> 2, q = tid & 3;
        const float4* pp = (const float4*)(part + ((size_t)b * 64 + c) * NBa + q * 128);
        float sm = 0.f;
        #pragma unroll
        for (int i = 0; i < 32; ++i) { float4 f = pp[i]; sm += f.x + f.y + f.z + f.w; }
        sm += __shfl_xor(sm, 1);
        sm += __shfl_xor(sm, 2);
        if (q == 0) pooled[c] = sm * (1.0f / NV);
        __syncthreads();
        if (tid < 4) {
            float a = cg_b1[tid];
            for (int cc = 0; cc < 64; ++cc) a += pooled[cc] * cg_w1[tid * 64 + cc];
            float sc = cg_bng[tid] * rsqrtf(cg_bnv[tid] + EPSBN);
            h[tid] = fmaxf((a - cg_bnm[tid]) * sc + cg_bnb[tid], 0.f);
        }
        __syncthreads();
        if (tid < 64) {
            float a = cg_b2[tid];
            #pragma unroll
            for (int r = 0; r < 4; ++r) a += h[r] * cg_w2[tid * 4 + r];
            ec[b * 64 + tid] = __expf(-a);
        }
        return;
    }

    __shared__ float4 wl4[108];      // [t*4 + r] = (w[r][0][t], w[r][1][t], w[r][2][t], w[r][3][t])
    if (tid < 108) {
        const int t = tid >> 2, r = tid & 3;
        wl4[tid] = make_float4(w[r * 108 +      t], w[r * 108 +  27 + t],
                               w[r * 108 + 54 + t], w[r * 108 +  81 + t]);
    }
    float cAr[4], cBr[4];
    #pragma unroll
    for (int r = 0; r < 4; ++r) {
        float sc = g[r] * rsqrtf(vv[r] + EPSBN);
        cAr[r] = sc;
        cBr[r] = (bias[r] - m[r]) * sc + be[r];
    }
    __syncthreads();

    const int v = blockIdx.x * 512 + tid * 2;
    const int x = v & 63, y = (v >> 6) & 63, z = v >> 12;
    const float4* pin = (const float4*)sin_ + (size_t)b * NV;

    float acc[2][4] = {};
    #pragma unroll
    for (int kz = -1; kz <= 1; ++kz) {
        const int zz = z + 4 * kz;
        if ((unsigned)zz >= 64u) continue;
        #pragma unroll
        for (int ky = -1; ky <= 1; ++ky) {
            const int yy = y + 4 * ky;
            if ((unsigned)yy >= 64u) continue;
            #pragma unroll
            for (int kx = -1; kx <= 1; ++kx) {
                const int xx = x + 4 * kx;
                if ((unsigned)xx >= 64u) continue;
                const int t = (kz + 1) * 9 + (ky + 1) * 3 + (kx + 1);
                const int vt = zz * 4096 + yy * 64 + xx;
                const float4 w0 = wl4[t * 4 + 0];
                const float4 w1 = wl4[t * 4 + 1];
                const float4 w2 = wl4[t * 4 + 2];
                const float4 w3 = wl4[t * 4 + 3];
                #pragma unroll
                for (int vi = 0; vi < 2; ++vi) {
                    const float4 tap = pin[vt + vi];
                    acc[vi][0] += w0.x * tap.x + w0.y * tap.y + w0.z * tap.z + w0.w * tap.w;
                    acc[vi][1] += w1.x * tap.x + w1.y * tap.y + w1.z * tap.z + w1.w * tap.w;
                    acc[vi][2] += w2.x * tap.x + w2.y * tap.y + w2.z * tap.z + w2.w * tap.w;
                    acc[vi][3] += w3.x * tap.x + w3.y * tap.y + w3.z * tap.z + w3.w * tap.w;
                }
            }
        }
    }

    float4* po = (float4*)outp + (size_t)b * NV + v;
    #pragma unroll
    for (int vi = 0; vi < 2; ++vi)
        po[vi] = make_float4(fmaxf(acc[vi][0] * cAr[0] + cBr[0], 0.f),
                             fmaxf(acc[vi][1] * cAr[1] + cBr[1], 0.f),
                             fmaxf(acc[vi][2] * cAr[2] + cBr[2], 0.f),
                             fmaxf(acc[vi][3] * cAr[3] + cBr[3], 0.f));
}

// ---------------------------------------------------------------------------
// kConv2: dilated conv2 + BN + ReLU + conv3 (1x1x1) -> es = e^{-att_s}
// ---------------------------------------------------------------------------
__global__ __launch_bounds__(256) void kConv2(
    const float* __restrict__ sin_,
    const float* __restrict__ w, const float* __restrict__ bias,
    const float* __restrict__ g, const float* __restrict__ be,
    const float* __restrict__ m, const float* __restrict__ vv,
    const float* __restrict__ w3, const float* __restrict__ b3,
    float* __restrict__ es)
{
    const int tid = threadIdx.x;
    __shared__ float4 wl4[108];
    if (tid < 108) {
        const int t = tid >> 2, r = tid & 3;
        wl4[tid] = make_float4(w[r * 108 +      t], w[r * 108 +  27 + t],
                               w[r * 108 + 54 + t], w[r * 108 +  81 + t]);
    }
    float cAr[4], cBr[4], w3l[4];
    #pragma unroll
    for (int r = 0; r < 4; ++r) {
        float sc = g[r] * rsqrtf(vv[r] + EPSBN);
        cAr[r] = sc;
        cBr[r] = (bias[r] - m[r]) * sc + be[r];
        w3l[r] = w3[r];
    }
    const float b3l = b3[0];
    __syncthreads();

    const int b = blockIdx.y;
    const int v = blockIdx.x * 512 + tid * 2;
    const int x = v & 63, y = (v >> 6) & 63, z = v >> 12;
    const float4* pin = (const float4*)sin_ + (size_t)b * NV;

    float acc[2][4] = {};
    #pragma unroll
    for (int kz = -1; kz <= 1; ++kz) {
        const int zz = z + 4 * kz;
        if ((unsigned)zz >= 64u) continue;
        #pragma unroll
        for (int ky = -1; ky <= 1; ++ky) {
            const int yy = y + 4 * ky;
            if ((unsigned)yy >= 64u) continue;
            #pragma unroll
            for (int kx = -1; kx <= 1; ++kx) {
                const int xx = x + 4 * kx;
                if ((unsigned)xx >= 64u) continue;
                const int t = (kz + 1) * 9 + (ky + 1) * 3 + (kx + 1);
                const int vt = zz * 4096 + yy * 64 + xx;
                const float4 w0 = wl4[t * 4 + 0];
                const float4 w1 = wl4[t * 4 + 1];
                const float4 w2 = wl4[t * 4 + 2];
                const float4 w3q = wl4[t * 4 + 3];
                #pragma unroll
                for (int vi = 0; vi < 2; ++vi) {
                    const float4 tap = pin[vt + vi];
                    acc[vi][0] += w0.x * tap.x + w0.y * tap.y + w0.z * tap.z + w0.w * tap.w;
                    acc[vi][1] += w1.x * tap.x + w1.y * tap.y + w1.z * tap.z + w1.w * tap.w;
                    acc[vi][2] += w2.x * tap.x + w2.y * tap.y + w2.z * tap.z + w2.w * tap.w;
                    acc[vi][3] += w3q.x * tap.x + w3q.y * tap.y + w3q.z * tap.z + w3q.w * tap.w;
                }
            }
        }
    }

    float ev[2];
    #pragma unroll
    for (int vi = 0; vi < 2; ++vi) {
        float r0 = fmaxf(acc[vi][0] * cAr[0] + cBr[0], 0.f);
        float r1 = fmaxf(acc[vi][1] * cAr[1] + cBr[1], 0.f);
        float r2 = fmaxf(acc[vi][2] * cAr[2] + cBr[2], 0.f);
        float r3 = fmaxf(acc[vi][3] * cAr[3] + cBr[3], 0.f);
        ev[vi] = __expf(-(b3l + w3l[0] * r0 + w3l[1] * r1 + w3l[2] * r2 + w3l[3] * r3));
    }
    *(float2*)(es + (size_t)b * NV + v) = make_float2(ev[0], ev[1]);
}

// ---------------------------------------------------------------------------
// kMul: pure streaming.  out[idx] = in[idx] * (1 + 1/(1 + ec[b,c]*es[b,v]))
// ---------------------------------------------------------------------------
__global__ __launch_bounds__(256) void kMul(
    const float* __restrict__ x1,
    const float* __restrict__ dwtM,
    const float* __restrict__ es,
    const float* __restrict__ ec,
    float* __restrict__ out0)
{
    const int i0 = blockIdx.x * 256 + threadIdx.x;   // [0, 524288)
    #pragma unroll 4
    for (int it = 0; it < 16; ++it) {
        const size_t idx = (size_t)i0 + (size_t)it * 524288;  // float4 index
        const int b  = (int)(idx >> 22);
        const int r  = (int)(idx & 4194303);
        const int c  = r >> 16;
        const int vq = r & 65535;
        const float* base = (c < 4)
            ? dwtM + ((size_t)b * 4 + c) * NV
            : x1   + ((size_t)b * C1 + (c - 4)) * NV;
        const float4 in4 = *(const float4*)(base + (size_t)vq * 4);
        const float4 es4 = ((const float4*)(es + (size_t)b * NV))[vq];
        const float  e   = ec[(b << 6) + c];
        f32x4 o;
        o.x = in4.x * (1.f + __builtin_amdgcn_rcpf(1.f + e * es4.x));
        o.y = in4.y * (1.f + __builtin_amdgcn_rcpf(1.f + e * es4.y));
        o.z = in4.z * (1.f + __builtin_amdgcn_rcpf(1.f + e * es4.z));
        o.w = in4.w * (1.f + __builtin_amdgcn_rcpf(1.f + e * es4.w));
        __builtin_nontemporal_store(o, (f32x4*)out0 + idx);
    }
}

// ---------------------------------------------------------------------------
extern "C" void kernel_launch(void* const* d_in, const int* in_sizes, int n_in,
                              void* d_out, int out_size, void* d_ws, size_t ws_size,
                              hipStream_t stream)
{
    const float* x1 = (const float*)d_in[0];
    const float* x2 = (const float*)d_in[1];
    const float* bn_g = (const float*)d_in[2];
    const float* bn_b = (const float*)d_in[3];
    const float* bn_m = (const float*)d_in[4];
    const float* bn_v = (const float*)d_in[5];
    const float* cg_w1 = (const float*)d_in[6];
    const float* cg_b1 = (const float*)d_in[7];
    const float* cg_bng = (const float*)d_in[8];
    const float* cg_bnb = (const float*)d_in[9];
    const float* cg_bnm = (const float*)d_in[10];
    const float* cg_bnv = (const float*)d_in[11];
    const float* cg_w2 = (const float*)d_in[12];
    const float* cg_b2 = (const float*)d_in[13];
    const float* sg_w0 = (const float*)d_in[14];
    const float* sg_b0 = (const float*)d_in[15];
    const float* sg_g0 = (const float*)d_in[16];
    const float* sg_be0 = (const float*)d_in[17];
    const float* sg_m0 = (const float*)d_in[18];
    const float* sg_v0 = (const float*)d_in[19];
    const float* sg_w1 = (const float*)d_in[20];
    const float* sg_b1 = (const float*)d_in[21];
    const float* sg_g1 = (const float*)d_in[22];
    const float* sg_be1 = (const float*)d_in[23];
    const float* sg_m1 = (const float*)d_in[24];
    const float* sg_v1 = (const float*)d_in[25];
    const float* sg_w2 = (const float*)d_in[26];
    const float* sg_b2 = (const float*)d_in[27];
    const float* sg_g2 = (const float*)d_in[28];
    const float* sg_be2 = (const float*)d_in[29];
    const float* sg_m2 = (const float*)d_in[30];
    const float* sg_v2 = (const float*)d_in[31];
    const float* sg_w3 = (const float*)d_in[32];
    const float* sg_b3 = (const float*)d_in[33];

    float* ws = (float*)d_ws;
    float* dwtM = ws;                 // 2*4*NV   = 2,097,152
    float* s0   = ws + 2097152;       //            2,097,152
    float* s1   = ws + 4194304;       //            2,097,152
    float* es   = ws + 6291456;       // B*NV     =   524,288
    float* part = ws + 6815744;       // B*64*NBa =    65,536
    float* ec   = ws + 6881280;       //                  128

    float* out0  = (float*)d_out;
    float* outLL = out0 + (size_t)B * 64 * NV;

    dim3 blk(256);
    kA<<<dim3(NBa, B), blk, 0, stream>>>(x1, x2, bn_g, bn_b, bn_m, bn_v,
                                         sg_w0, sg_b0, sg_g0, sg_be0, sg_m0, sg_v0,
                                         dwtM, s0, part, outLL);
    kConv1<<<dim3(NBa + 1, B), blk, 0, stream>>>(s0, sg_w1, sg_b1, sg_g1, sg_be1, sg_m1, sg_v1,
                                                 part, cg_w1, cg_b1, cg_bng, cg_bnb, cg_bnm, cg_bnv,
                                                 cg_w2, cg_b2, ec, s1);
    kConv2<<<dim3(NBa, B), blk, 0, stream>>>(s1, sg_w2, sg_b2, sg_g2, sg_be2, sg_m2, sg_v2,
                                             sg_w3, sg_b3, es);
    kMul<<<dim3(2048), blk, 0, stream>>>(x1, dwtM, es, ec, out0);
}